// Round 8
// baseline (20149.742 us; speedup 1.0000x reference)
//
#include <hip/hip_runtime.h>
#include <math.h>

#define NN 100000
#define EE 1600000

// Round 6/7/8: LDS-staged weights (kept from r5) + LANE-PAIR edge split.
// r5 failed: compiler capped VGPR at 128 and spilled the ~150-float live set
// (FETCH 595MB->4.1GB = scratch reloads missing L2). Pair split halves the
// live arrays to ~100 regs -> fits 128 VGPR. 512-thr blocks keep LDS/CU at
// 125KB but double waves/SIMD to 4. launch_bounds(512,4) pins the 128 cap.

__device__ __forceinline__ float silu_f(float x) {
    const float e = __expf(-x);
    return x * __builtin_amdgcn_rcpf(1.0f + e);
}

// acc[0..31] += x * w[0..31]  (w = row base already offset to this lane's j0)
__device__ __forceinline__ void fmarow32(float* acc, const float x, const float* __restrict__ w) {
#pragma unroll
    for (int c = 0; c < 8; ++c) {
        const float4 wv = *reinterpret_cast<const float4*>(w + 4 * c);
        acc[4 * c + 0] = fmaf(x, wv.x, acc[4 * c + 0]);
        acc[4 * c + 1] = fmaf(x, wv.y, acc[4 * c + 1]);
        acc[4 * c + 2] = fmaf(x, wv.z, acc[4 * c + 2]);
        acc[4 * c + 3] = fmaf(x, wv.w, acc[4 * c + 3]);
    }
}

// acc[0..31] += x_vec[0..4*NV) @ W rows (W row-major [*,64], pre-offset +j0)
template <int NV>
__device__ __forceinline__ void seg32(float* acc, const float4* __restrict__ xsrc,
                                      const float* __restrict__ w) {
#pragma unroll 1
    for (int c = 0; c < NV; ++c) {
        const float4 xv = xsrc[c];
        const float* wr = w + (size_t)(4 * c) * 64;
        fmarow32(acc, xv.x, wr);
        fmarow32(acc, xv.y, wr + 64);
        fmarow32(acc, xv.z, wr + 128);
        fmarow32(acc, xv.w, wr + 192);
    }
}

// acc[0..31] += t64 @ W, where t64 is distributed 32-per-lane across the pair.
// W pre-offset to +j0. Fully static unroll (shfl srcLane immediate -> DPP).
__device__ __forceinline__ void pgemm32(float* acc, const float* tloc,
                                        const float* __restrict__ w) {
#pragma unroll
    for (int ko = 0; ko < 2; ++ko) {
#pragma unroll
        for (int ki = 0; ki < 32; ++ki) {
            const float x = __shfl(tloc[ki], ko, 2);
            fmarow32(acc, x, w + (size_t)(ko * 32 + ki) * 64);
        }
    }
}

__global__ void __launch_bounds__(256)
init_kernel(const float* __restrict__ pos, float* __restrict__ m_i,
            float* __restrict__ pos_out)
{
    const int i = blockIdx.x * 256 + threadIdx.x;
    const float4 z = make_float4(0.f, 0.f, 0.f, 0.f);
    if (i < NN * 64 / 4) reinterpret_cast<float4*>(m_i)[i] = z;
    if (i < NN * 3 / 4)
        reinterpret_cast<float4*>(pos_out)[i] = reinterpret_cast<const float4*>(pos)[i];
}

// LDS: W1[177*64]=11328f, W2[64*64]=4096f, B[256]: eb1|eb2|cb1|cw2  = 62720 B
__global__ void __launch_bounds__(512, 4)
edge_kernel(const float* __restrict__ h, const float* __restrict__ pos,
            const float* __restrict__ ea, const float* __restrict__ te,
            const int* __restrict__ ei,
            const float* __restrict__ ew1, const float* __restrict__ eb1,
            const float* __restrict__ ew2, const float* __restrict__ eb2,
            const float* __restrict__ cw1, const float* __restrict__ cb1,
            const float* __restrict__ cw2,
            float* __restrict__ m_i, float* __restrict__ pos_out)
{
    extern __shared__ float lds[];
    float* W1 = lds;             // 11328
    float* W2 = lds + 11328;     // 4096
    float* B  = lds + 15424;     // 256

    const int t = threadIdx.x;
    {   // stage weights once per block
        const float4* s1 = reinterpret_cast<const float4*>(ew1);
        float4* d1 = reinterpret_cast<float4*>(W1);
        for (int i = t; i < 11328 / 4; i += 512) d1[i] = s1[i];
        const float4* s2 = reinterpret_cast<const float4*>(ew2);
        float4* d2 = reinterpret_cast<float4*>(W2);
        for (int i = t; i < 4096 / 4; i += 512) d2[i] = s2[i];
        if (t < 64) { B[t] = eb1[t]; B[64 + t] = eb2[t]; B[128 + t] = cb1[t]; B[192 + t] = cw2[t]; }
    }
    __syncthreads();

    const int p  = t & 1;        // parity: which 32 output features
    const int j0 = p << 5;
    const float* W1j = W1 + j0;
    const float* W2j = W2 + j0;

    const int pairs_per_blk = 512 / 2;
    const int stride = gridDim.x * pairs_per_blk;
    for (int e = blockIdx.x * pairs_per_blk + (t >> 1); e < EE; e += stride) {
        const int row = ei[e];
        const int col = ei[EE + e];

        const float rx = pos[3 * row + 0] - pos[3 * col + 0];
        const float ry = pos[3 * row + 1] - pos[3 * col + 1];
        const float rz = pos[3 * row + 2] - pos[3 * col + 2];
        const float dist = sqrtf(rx * rx + ry * ry + rz * rz);

        // ---- layer 1: edge_input[177] @ W1 + eb1 (my 32 cols) ----
        float acc[32];
#pragma unroll
        for (int j = 0; j < 32; ++j) acc[j] = B[j0 + j];
        seg32<16>(acc, reinterpret_cast<const float4*>(h + (size_t)row * 64), W1j);
        seg32<16>(acc, reinterpret_cast<const float4*>(h + (size_t)col * 64), W1j + 64 * 64);
        seg32<4>(acc, reinterpret_cast<const float4*>(ea + (size_t)e * 16), W1j + 128 * 64);
        fmarow32(acc, dist, W1j + 144 * 64);
        seg32<8>(acc, reinterpret_cast<const float4*>(te + (size_t)row * 32), W1j + 145 * 64);

        float tt[32];
#pragma unroll
        for (int j = 0; j < 32; ++j) tt[j] = silu_f(acc[j]);

        // ---- layer 2: silu(t64 @ W2 + eb2) = m (my 32) ----
        float m[32];
#pragma unroll
        for (int j = 0; j < 32; ++j) m[j] = B[64 + j0 + j];
        pgemm32(m, tt, W2j);
#pragma unroll
        for (int j = 0; j < 32; ++j) m[j] = silu_f(m[j]);

        // ---- scatter my 32 of m_ij -> m_i[col] ----
        float* md = m_i + (size_t)col * 64 + j0;
#pragma unroll
        for (int j = 0; j < 32; ++j) unsafeAtomicAdd(md + j, m[j]);

        // ---- coord MLP: silu(m64 @ cw1 + cb1) . cw2 ----
        // cw1 (16KB) from global: 2 addrs/wave, L1-resident
        float a3[32];
#pragma unroll
        for (int j = 0; j < 32; ++j) a3[j] = B[128 + j0 + j];
        pgemm32(a3, m, cw1 + j0);

        float part = 0.0f;
#pragma unroll
        for (int j = 0; j < 32; ++j) part += silu_f(a3[j]) * B[192 + j0 + j];
        part += __shfl_xor(part, 1, 2);   // pair sum -> both lanes

        if (p == 0) {
            const float s = part / (dist + 1e-8f);
            unsafeAtomicAdd(&pos_out[3 * (size_t)col + 0], s * rx);
            unsafeAtomicAdd(&pos_out[3 * (size_t)col + 1], s * ry);
            unsafeAtomicAdd(&pos_out[3 * (size_t)col + 2], s * rz);
        }
    }
}

// LDS: NW1[160*64]=10240f, NW2[64*64]=4096f, B[256]: nb1|nb2|sb|tb = 58368 B
__global__ void __launch_bounds__(512, 4)
node_kernel(const float* __restrict__ h, const float* __restrict__ te,
            const float* __restrict__ m_i,
            const float* __restrict__ nw1, const float* __restrict__ nb1,
            const float* __restrict__ nw2, const float* __restrict__ nb2,
            const float* __restrict__ sw, const float* __restrict__ sb,
            const float* __restrict__ tw, const float* __restrict__ tb,
            float* __restrict__ h_out)
{
    extern __shared__ float lds[];
    float* W1 = lds;             // 10240
    float* W2 = lds + 10240;     // 4096
    float* B  = lds + 14336;     // 256

    const int t = threadIdx.x;
    {
        const float4* s1 = reinterpret_cast<const float4*>(nw1);
        float4* d1 = reinterpret_cast<float4*>(W1);
        for (int i = t; i < 10240 / 4; i += 512) d1[i] = s1[i];
        const float4* s2 = reinterpret_cast<const float4*>(nw2);
        float4* d2 = reinterpret_cast<float4*>(W2);
        for (int i = t; i < 4096 / 4; i += 512) d2[i] = s2[i];
        if (t < 64) { B[t] = nb1[t]; B[64 + t] = nb2[t]; B[128 + t] = sb[t]; B[192 + t] = tb[t]; }
    }
    __syncthreads();

    const int p  = t & 1;
    const int j0 = p << 5;
    const float* W1j = W1 + j0;
    const float* W2j = W2 + j0;

    const int pairs_per_blk = 512 / 2;
    const int stride = gridDim.x * pairs_per_blk;
    for (int n = blockIdx.x * pairs_per_blk + (t >> 1); n < NN; n += stride) {
        const float4* hv  = reinterpret_cast<const float4*>(h + (size_t)n * 64);
        const float4* tev = reinterpret_cast<const float4*>(te + (size_t)n * 32);

        // ---- layer 1: [h, m_i, te] @ NW1 + nb1 ----
        float acc[32];
#pragma unroll
        for (int j = 0; j < 32; ++j) acc[j] = B[j0 + j];
        seg32<16>(acc, hv, W1j);
        seg32<16>(acc, reinterpret_cast<const float4*>(m_i + (size_t)n * 64), W1j + 64 * 64);
        seg32<8>(acc, tev, W1j + 128 * 64);

        float tt[32];
#pragma unroll
        for (int j = 0; j < 32; ++j) tt[j] = silu_f(acc[j]);

        // ---- layer 2: t64 @ NW2 + nb2 -> hu ----
        float hu[32];
#pragma unroll
        for (int j = 0; j < 32; ++j) hu[j] = B[64 + j0 + j];
        pgemm32(hu, tt, W2j);

        // ---- FiLM scale (te @ sw + sb): te held fully per lane ----
        float f[32];
#pragma unroll
        for (int j = 0; j < 32; ++j) f[j] = B[128 + j0 + j];
        seg32<8>(f, tev, sw + j0);
#pragma unroll
        for (int j = 0; j < 32; ++j) hu[j] *= f[j];

        // ---- FiLM shift (te @ tw + tb) ----
#pragma unroll
        for (int j = 0; j < 32; ++j) f[j] = B[192 + j0 + j];
        seg32<8>(f, tev, tw + j0);

        // ---- h_new = h + hu + f (my 32 cols) ----
        const float* hp = h + (size_t)n * 64 + j0;
        float* op = h_out + (size_t)n * 64 + j0;
#pragma unroll
        for (int c = 0; c < 8; ++c) {
            const float4 hx = *reinterpret_cast<const float4*>(hp + 4 * c);
            float4 o;
            o.x = hx.x + hu[4 * c + 0] + f[4 * c + 0];
            o.y = hx.y + hu[4 * c + 1] + f[4 * c + 1];
            o.z = hx.z + hu[4 * c + 2] + f[4 * c + 2];
            o.w = hx.w + hu[4 * c + 3] + f[4 * c + 3];
            *reinterpret_cast<float4*>(op + 4 * c) = o;
        }
    }
}

extern "C" void kernel_launch(void* const* d_in, const int* in_sizes, int n_in,
                              void* d_out, int out_size, void* d_ws, size_t ws_size,
                              hipStream_t stream)
{
    const float* h    = (const float*)d_in[0];
    const float* pos  = (const float*)d_in[1];
    const float* ea   = (const float*)d_in[2];
    const float* te   = (const float*)d_in[3];
    const int*   ei   = (const int*)d_in[4];
    const float* ew1  = (const float*)d_in[5];
    const float* eb1  = (const float*)d_in[6];
    const float* ew2  = (const float*)d_in[7];
    const float* eb2  = (const float*)d_in[8];
    const float* nw1  = (const float*)d_in[9];
    const float* nb1  = (const float*)d_in[10];
    const float* nw2  = (const float*)d_in[11];
    const float* nb2  = (const float*)d_in[12];
    const float* cw1  = (const float*)d_in[13];
    const float* cb1  = (const float*)d_in[14];
    const float* cw2  = (const float*)d_in[15];
    const float* sw   = (const float*)d_in[16];
    const float* sb   = (const float*)d_in[17];
    const float* tw   = (const float*)d_in[18];
    const float* tb   = (const float*)d_in[19];

    float* h_out   = (float*)d_out;
    float* pos_out = (float*)d_out + (size_t)NN * 64;
    float* m_i     = (float*)d_ws;   // [N,64] accumulator

    init_kernel<<<(NN * 64 / 4 + 255) / 256, 256, 0, stream>>>(pos, m_i, pos_out);

    // 512 blocks x 512 thr: 2 blocks/CU (125KB LDS), 16 waves/CU, grid-stride
    edge_kernel<<<512, 512, 62720, stream>>>(h, pos, ea, te, ei,
                                             ew1, eb1, ew2, eb2,
                                             cw1, cb1, cw2,
                                             m_i, pos_out);

    node_kernel<<<(NN * 2 + 511) / 512, 512, 58368, stream>>>(h, te, m_i,
                                                              nw1, nb1, nw2, nb2,
                                                              sw, sb, tw, tb, h_out);
}